// Round 16
// baseline (172.700 us; speedup 1.0000x reference)
//
#include <hip/hip_runtime.h>
#include <hip/hip_bf16.h>

#define B_   16
#define T_   512
#define C_   1080
#define H_   20
#define HD_  54
#define DP_  64                 // padded head dim
#define M_   (B_ * T_)          // 8192
#define KP_  1088               // padded K
#define NT_  17                 // K tiles of 64 (proj kernel)
#define NT32_ 34                // K tiles of 32 (QKV kernel)
#define NQKV_ 3840              // padded 3C: 3 * 20 * 64
#define NPRJ_ 1152              // padded C (9*128)
#define NBT_ (B_ * H_ * T_)     // 163840

typedef short bf16x8 __attribute__((ext_vector_type(8)));
typedef float f32x4  __attribute__((ext_vector_type(4)));
typedef unsigned short u16x8 __attribute__((ext_vector_type(8)));

__device__ __forceinline__ void gload_lds16(const void* g, void* l) {
    __builtin_amdgcn_global_load_lds(
        (const __attribute__((address_space(1))) void*)g,
        (__attribute__((address_space(3))) void*)l,
        16, 0, 0);
}

__device__ __forceinline__ unsigned short f2b(float x) {
    return __builtin_bit_cast(unsigned short, __float2bfloat16(x));
}

// ---------------------------------------------------------------------------
// prep_all: (a) x -> xb bf16 cvt+pad, (b) W_attn -> wta head-padded transpose,
// (c) W_proj -> wtp transpose, (d) padded bias with V ones-column d=63.
// ---------------------------------------------------------------------------
#define PB_CVT  8704            // M_*(KP_/4)/256
#define PB_WTA  4080            // 120*34
#define PB_WTP  1224            // 36*34
__global__ __launch_bounds__(256) void prep_all(
    const float* __restrict__ x, const float* __restrict__ W_attn,
    const float* __restrict__ W_proj, const float* __restrict__ b_attn,
    __hip_bfloat16* __restrict__ xb,
    __hip_bfloat16* __restrict__ wta, __hip_bfloat16* __restrict__ wtp,
    float* __restrict__ bp)
{
    __shared__ float tile[32][33];
    int id = blockIdx.x;

    if (id < PB_CVT) {
        int idx = id * 256 + threadIdx.x;
        int m = idx / (KP_ / 4), c = idx - m * (KP_ / 4);
        ushort4 o;
        if (c < C_ / 4) {
            float4 v = *reinterpret_cast<const float4*>(x + (size_t)m * C_ + c * 4);
            o.x = f2b(v.x); o.y = f2b(v.y); o.z = f2b(v.z); o.w = f2b(v.w);
        } else {
            o.x = o.y = o.z = o.w = 0;
        }
        *reinterpret_cast<ushort4*>(reinterpret_cast<unsigned short*>(xb) +
                                    (size_t)m * KP_ + c * 4) = o;
        return;
    }
    id -= PB_CVT;
    const int tx = threadIdx.x & 31, ty = threadIdx.x >> 5;

    if (id < PB_WTA) {
        int bx = id % 120, by = id / 120;
        int n0 = bx * 32, k0 = by * 32;
        int np = n0 + tx;
        int which = np / 1280;
        int rem = np - which * 1280;
        int h = rem >> 6, d = rem & 63;
        int sn = which * C_ + h * HD_ + d;
        bool valid = d < HD_;
        #pragma unroll
        for (int i = 0; i < 32; i += 8) {
            int k = k0 + ty + i;
            tile[ty + i][tx] = (valid && k < C_) ? W_attn[(size_t)k * (3 * C_) + sn] : 0.f;
        }
        __syncthreads();
        #pragma unroll
        for (int i = 0; i < 32; i += 8) {
            int n = n0 + ty + i, k = k0 + tx;
            wta[(size_t)n * KP_ + k] = __float2bfloat16(tile[tx][ty + i]);
        }
        return;
    }
    id -= PB_WTA;

    if (id < PB_WTP) {
        int bx = id % 36, by = id / 36;
        int n0 = bx * 32, k0 = by * 32;
        #pragma unroll
        for (int i = 0; i < 32; i += 8) {
            int k = k0 + ty + i, n = n0 + tx;
            tile[ty + i][tx] = (k < C_ && n < C_) ? W_proj[(size_t)k * C_ + n] : 0.f;
        }
        __syncthreads();
        #pragma unroll
        for (int i = 0; i < 32; i += 8) {
            int n = n0 + ty + i, k = k0 + tx;
            wtp[(size_t)n * KP_ + k] = __float2bfloat16(tile[tx][ty + i]);
        }
        return;
    }
    id -= PB_WTP;

    {
        int i = id * 256 + threadIdx.x;
        if (i < NQKV_) {
            int which = i / 1280, rem = i - which * 1280;
            int h = rem >> 6, d = rem & 63;
            float v = (d < HD_) ? b_attn[which * C_ + h * HD_ + d] : 0.f;
            if (which == 2 && d == 63) v = 1.0f;
            bp[i] = v;
        }
    }
}

// ---------------------------------------------------------------------------
// 256x256 8-wave MFMA GEMM for QKV, BK=32 ring-2 (64KB compute LDS -> 2
// blocks/CU co-resident, all 480 blocks in one dispatch round). Per K-tile:
// stage 4 gload_lds | vmcnt(4) | barrier | 12 ds_read + 32 MFMA | barrier.
// __launch_bounds__(512, 2): natural VGPR ~116 <= 128 so HW still co-schedules
// 4 waves/SIMD -- the (512,4) bound in r11 capped VGPR at 128 and spilled acc
// (catastrophic); do NOT restore it.
// ---------------------------------------------------------------------------
__global__ __launch_bounds__(512, 2) void gemm256(
    const unsigned short* __restrict__ A,
    const unsigned short* __restrict__ Bt,
    const float* __restrict__ bias,
    unsigned short* __restrict__ outQ,
    unsigned short* __restrict__ outK,
    unsigned short* __restrict__ outV)
{
    __shared__ __align__(16) char smem[69632];   // 2x32KB ring + V-transpose union

    const int tid  = threadIdx.x;
    const int lane = tid & 63;
    const int wv   = tid >> 6;
    const int wr   = wv >> 2;          // m-half 0..1
    const int wc   = wv & 3;           // n-quarter 0..3
    const int lq   = lane & 15;
    const int lg   = lane >> 4;

    // XCD swizzle: 480 blocks, chunk = 4 m-tiles, m-fastest walk
    const int id  = blockIdx.y * 15 + blockIdx.x;
    const int xcd = id & 7;
    const int j   = id >> 3;
    const int m0  = (xcd * 4 + (j & 3)) * 256;
    const int n0  = (j >> 2) * 256;

    // staging: 1024 16B-chunks per operand-tile (256 rows x 4 chunks); 2 each
    unsigned aOff[2], bOff[2];
    int dA[2];
    #pragma unroll
    for (int i = 0; i < 2; ++i) {
        int ci = tid + i * 512;
        int r  = ci >> 2, c = ci & 3;
        int kc = c ^ (r & 3);
        aOff[i] = (unsigned)(m0 + r) * KP_ + kc * 8;
        bOff[i] = (unsigned)(n0 + r) * KP_ + kc * 8;
        dA[i] = ci * 16;
    }

    auto stage = [&](int buf, unsigned k0) {
        char* sb = smem + buf * 32768;
        gload_lds16(A + aOff[0] + k0, sb + dA[0]);
        gload_lds16(A + aOff[1] + k0, sb + dA[1]);
        gload_lds16(Bt + bOff[0] + k0, sb + 16384 + dA[0]);
        gload_lds16(Bt + bOff[1] + k0, sb + 16384 + dA[1]);
    };

    // ds_read bases: row*64 + slot*16; row&3 == lq&3 (wr*128, mi*16 = 0 mod 4)
    const int s0 = (lg ^ (lq & 3)) * 16;
    const int aBase = wr * 8192 + lq * 64 + s0;
    const int bBase = 16384 + wc * 4096 + lq * 64 + s0;

    f32x4 acc[8][4] = {};

    stage(0, 0);
    for (int t = 0; t < NT32_; ++t) {
        const int cur = t & 1;
        if (t + 1 < NT32_) {
            stage(cur ^ 1, (unsigned)(t + 1) * 32);
            asm volatile("s_waitcnt vmcnt(4)" ::: "memory");   // tile t's loads done
        } else {
            asm volatile("s_waitcnt vmcnt(0)" ::: "memory");
        }
        __builtin_amdgcn_s_barrier();

        const char* Ab = smem + cur * 32768 + aBase;
        const char* Bb = smem + cur * 32768 + bBase;

        bf16x8 bfr[4];
        #pragma unroll
        for (int ni = 0; ni < 4; ++ni)
            bfr[ni] = *reinterpret_cast<const bf16x8*>(Bb + ni * 1024);
        bf16x8 af[8];
        #pragma unroll
        for (int mi = 0; mi < 8; ++mi)
            af[mi] = *reinterpret_cast<const bf16x8*>(Ab + mi * 1024);

        __builtin_amdgcn_s_setprio(1);
        #pragma unroll
        for (int mi = 0; mi < 8; ++mi)
            #pragma unroll
            for (int ni = 0; ni < 4; ++ni)
                acc[mi][ni] = __builtin_amdgcn_mfma_f32_16x16x32_bf16(
                    af[mi], bfr[ni], acc[mi][ni], 0, 0, 0);
        __builtin_amdgcn_s_setprio(0);
        __builtin_amdgcn_s_barrier();
    }

    // epilogue
    const int which = n0 / 1280;       // block-uniform (1280 % 256 == 0)
    if (which < 2) {
        unsigned short* dst = which ? outK : outQ;
        #pragma unroll
        for (int mi = 0; mi < 8; ++mi) {
            int mg = m0 + wr * 128 + mi * 16 + lg * 4;
            int b = mg >> 9, t0 = mg & (T_ - 1);
            #pragma unroll
            for (int ni = 0; ni < 4; ++ni) {
                int nl = wc * 64 + ni * 16 + lq;
                int ng = n0 + nl - which * 1280;
                int h = ng >> 6, d = ng & 63;
                float bs = bias[n0 + nl];
                size_t basei = ((size_t)(b * H_ + h) * T_ + t0) * DP_ + d;
                #pragma unroll
                for (int j2 = 0; j2 < 4; ++j2)
                    dst[basei + (size_t)j2 * DP_] = f2b(acc[mi][ni][j2] + bs);
            }
        }
    } else {
        // V: 2-pass (m-half) skewed LDS transpose + 16B coalesced stores
        unsigned short* lt = (unsigned short*)smem;   // [256 n][136 m-half]
        #pragma unroll
        for (int hm = 0; hm < 2; ++hm) {
            if (hm == 1) __syncthreads();
            if (wr == hm) {
                #pragma unroll
                for (int mi = 0; mi < 8; ++mi) {
                    int ml = mi * 16 + lg * 4;
                    int mc = ml >> 3, mo = ml & 7;
                    #pragma unroll
                    for (int ni = 0; ni < 4; ++ni) {
                        int nl = wc * 64 + ni * 16 + lq;
                        float bs = bias[n0 + nl];
                        ushort4 pk;
                        pk.x = f2b(acc[mi][ni][0] + bs);
                        pk.y = f2b(acc[mi][ni][1] + bs);
                        pk.z = f2b(acc[mi][ni][2] + bs);
                        pk.w = f2b(acc[mi][ni][3] + bs);
                        int slot = mc ^ ((nl >> 3) & 15);
                        *reinterpret_cast<ushort4*>(lt + nl * 136 + slot * 8 + mo) = pk;
                    }
                }
            }
            __syncthreads();
            #pragma unroll
            for (int it = 0; it < 8; ++it) {
                int idx = it * 512 + tid;
                int c2 = idx >> 4, j2 = idx & 15;
                int slot = j2 ^ ((c2 >> 3) & 15);
                u16x8 v = *reinterpret_cast<const u16x8*>(lt + c2 * 136 + slot * 8);
                int ng = n0 + c2 - 2560;
                int h = ng >> 6, d = ng & 63;
                int mg = m0 + hm * 128 + j2 * 8;
                int b = mg >> 9, t = mg & (T_ - 1);
                *reinterpret_cast<u16x8*>(outV + ((size_t)(b * H_ + h) * DP_ + d) * T_ + t) = v;
            }
        }
    }
}

// ---------------------------------------------------------------------------
// 128x128 bf16 MFMA GEMM (proj): ring-2 LDS, counted vmcnt(8), hoisted addrs.
// ---------------------------------------------------------------------------
__global__ __launch_bounds__(256) void gemm_mfma_p(
    const unsigned short* __restrict__ A,
    const unsigned short* __restrict__ Bt,
    const float* __restrict__ bias,
    float* __restrict__ outP)
{
    __shared__ __align__(16) char smem[65536];

    const int tid  = threadIdx.x;
    const int lane = tid & 63;
    const int wv   = tid >> 6;
    const int wm   = (wv >> 1) * 64;
    const int wn   = (wv & 1) * 64;
    const int lr   = lane & 15;
    const int lk   = lane >> 4;

    const int gx  = gridDim.x;
    const int gy  = gridDim.y;
    const int id  = blockIdx.y * gx + blockIdx.x;
    const int xcd = id & 7;
    const int j   = id >> 3;
    const int mpc = gy >> 3;
    const int m0  = (xcd * mpc + j % mpc) * 128;
    const int n0  = (j / mpc) * 128;

    unsigned aOff[4], bOff[4];
    int ciB[4];
    #pragma unroll
    for (int it = 0; it < 4; ++it) {
        int ci = it * 256 + tid;
        int r = ci >> 3, p = ci & 7;
        int kc = p ^ (r & 7);
        aOff[it] = (unsigned)(m0 + r) * KP_ + kc * 8;
        bOff[it] = (unsigned)(n0 + r) * KP_ + kc * 8;
        ciB[it] = ci * 16;
    }
    int aRd[2][4], bRd[2][4];
    #pragma unroll
    for (int kk = 0; kk < 2; ++kk) {
        #pragma unroll
        for (int mi = 0; mi < 4; ++mi) {
            int row = wm + mi * 16 + lr;
            aRd[kk][mi] = row * 128 + ((kk * 4 + lk) ^ (row & 7)) * 16;
            int rowb = wn + mi * 16 + lr;
            bRd[kk][mi] = 16384 + rowb * 128 + ((kk * 4 + lk) ^ (rowb & 7)) * 16;
        }
    }

    f32x4 acc[4][4] = {};

    auto stage = [&](int buf, int kt) {
        const unsigned k0 = kt * 64;
        char* sb = smem + buf * 32768;
        #pragma unroll
        for (int it = 0; it < 4; ++it)
            gload_lds16(A + aOff[it] + k0, sb + ciB[it]);
        #pragma unroll
        for (int it = 0; it < 4; ++it)
            gload_lds16(Bt + bOff[it] + k0, sb + 16384 + ciB[it]);
    };

    stage(0, 0);
    for (int kt = 0; kt < NT_; ++kt) {
        const int c = kt & 1;
        if (kt + 1 < NT_) {
            stage(1 - c, kt + 1);
            asm volatile("s_waitcnt vmcnt(8)" ::: "memory");
        } else {
            asm volatile("s_waitcnt vmcnt(0)" ::: "memory");
        }
        __builtin_amdgcn_s_barrier();
        asm volatile("" ::: "memory");

        const char* base = smem + c * 32768;
        #pragma unroll
        for (int kk = 0; kk < 2; ++kk) {
            bf16x8 af[4], bfr[4];
            #pragma unroll
            for (int mi = 0; mi < 4; ++mi)
                af[mi] = *reinterpret_cast<const bf16x8*>(base + aRd[kk][mi]);
            #pragma unroll
            for (int ni = 0; ni < 4; ++ni)
                bfr[ni] = *reinterpret_cast<const bf16x8*>(base + bRd[kk][ni]);
            #pragma unroll
            for (int mi = 0; mi < 4; ++mi)
                #pragma unroll
                for (int ni = 0; ni < 4; ++ni)
                    acc[mi][ni] = __builtin_amdgcn_mfma_f32_16x16x32_bf16(
                        af[mi], bfr[ni], acc[mi][ni], 0, 0, 0);
        }
        asm volatile("" ::: "memory");
        __builtin_amdgcn_s_barrier();
    }

    #pragma unroll
    for (int mi = 0; mi < 4; ++mi) {
        int mrow = m0 + wm + mi * 16 + lk * 4;
        #pragma unroll
        for (int ni = 0; ni < 4; ++ni) {
            int n = n0 + wn + ni * 16 + lr;
            if (n < C_) {
                float bs = bias[n];
                #pragma unroll
                for (int j2 = 0; j2 < 4; ++j2)
                    outP[(size_t)(mrow + j2) * C_ + n] = acc[mi][ni][j2] + bs;
            }
        }
    }
}

// ---------------------------------------------------------------------------
// MFMA flash attention, static-max softmax + ones-column l, 2 q-tiles/block.
// ---------------------------------------------------------------------------
__global__ __launch_bounds__(512) void attn_mfma(
    const unsigned short* __restrict__ Q, const unsigned short* __restrict__ K,
    const unsigned short* __restrict__ Vt, __hip_bfloat16* __restrict__ Y)
{
    __shared__ __align__(16) char kvs[16384];               // K tile | Vt tile
    __shared__ __align__(16) unsigned short ps[8][16][72];  // per-wave P

    const int tid  = threadIdx.x;
    const int lane = tid & 63;
    const int wv   = tid >> 6;          // 0..7
    const int grp  = wv >> 2;           // q-tile within pair
    const int wq   = wv & 3;            // wave within q-tile group
    const int lq   = lane & 15;
    const int lg   = lane >> 4;
    const int bh   = blockIdx.y;
    const int qt_own = blockIdx.x * 2 + grp;
    const int qbase  = qt_own * 64;
    const float cs = 0.13608276348795434f * 1.44269504f;  // (1/sqrt(54))*log2e

    bf16x8 qf[2];
    {
        const unsigned short* qp = Q + ((size_t)bh * T_ + qbase + wq * 16 + lq) * DP_;
        qf[0] = *reinterpret_cast<const bf16x8*>(qp + lg * 8);
        qf[1] = *reinterpret_cast<const bf16x8*>(qp + 32 + lg * 8);
    }

    const int sr = tid >> 3, sp = tid & 7;
    const int spc = sp ^ (sr & 7);
    const unsigned kOff = (unsigned)(sr * DP_ + spc * 8);
    const unsigned vOff = (unsigned)(sr * T_ + spc * 8);
    const unsigned short* Kb = K  + (size_t)bh * T_ * DP_;
    const unsigned short* Vb = Vt + (size_t)bh * DP_ * T_;

    f32x4 o[4] = {};
    unsigned short* pbase = &ps[wv][0][0];
    const int nt = blockIdx.x * 2 + 2;

    for (int kt = 0; kt < nt; ++kt) {
        const int kbase = kt * 64;
        gload_lds16(Kb + kOff + (unsigned)kbase * DP_, kvs + tid * 16);
        gload_lds16(Vb + vOff + (unsigned)kbase, kvs + 8192 + tid * 16);
        __syncthreads();

        if (kt <= qt_own) {               // wave-uniform causal tile guard
            f32x4 s[4] = {};
            __builtin_amdgcn_s_setprio(1);
            #pragma unroll
            for (int dc = 0; dc < 2; ++dc) {
                #pragma unroll
                for (int ni = 0; ni < 4; ++ni) {
                    int row = ni * 16 + lq;
                    int ch  = (dc * 4 + lg) ^ (row & 7);
                    bf16x8 kf = *reinterpret_cast<const bf16x8*>(kvs + row * 128 + ch * 16);
                    s[ni] = __builtin_amdgcn_mfma_f32_16x16x32_bf16(qf[dc], kf, s[ni], 0, 0, 0);
                }
            }
            __builtin_amdgcn_s_setprio(0);

            if (kt == qt_own) {
                #pragma unroll
                for (int ni = 0; ni < 4; ++ni) {
                    int kg = kbase + ni * 16 + lq;
                    #pragma unroll
                    for (int j = 0; j < 4; ++j) {
                        int qg = qbase + wq * 16 + lg * 4 + j;
                        s[ni][j] = (kg > qg) ? -3.0e38f : s[ni][j];
                    }
                }
            }
            #pragma unroll
            for (int ni = 0; ni < 4; ++ni) {
                #pragma unroll
                for (int j = 0; j < 4; ++j) {
                    float p = exp2f(s[ni][j] * cs);
                    int qr = lg * 4 + j;
                    int cidx = (ni * 2 + (lq >> 3)) ^ (qr & 7);
                    pbase[qr * 72 + cidx * 8 + (lq & 7)] = f2b(p);
                }
            }

            asm volatile("s_waitcnt lgkmcnt(0)" ::: "memory");
            __builtin_amdgcn_sched_barrier(0);

            __builtin_amdgcn_s_setprio(1);
            #pragma unroll
            for (int dc = 0; dc < 2; ++dc) {
                int cc = (dc * 4 + lg) ^ (lq & 7);
                bf16x8 pf = *reinterpret_cast<const bf16x8*>(pbase + lq * 72 + cc * 8);
                #pragma unroll
                for (int ni = 0; ni < 4; ++ni) {
                    int row = ni * 16 + lq;
                    int ch  = (dc * 4 + lg) ^ (row & 7);
                    bf16x8 vf = *reinterpret_cast<const bf16x8*>(kvs + 8192 + row * 128 + ch * 16);
                    o[ni] = __builtin_amdgcn_mfma_f32_16x16x32_bf16(pf, vf, o[ni], 0, 0, 0);
                }
            }
            __builtin_amdgcn_s_setprio(0);
        }
        __syncthreads();
    }

    const int b = bh / H_, h = bh - b * H_;
    #pragma unroll
    for (int j = 0; j < 4; ++j) {
        float l = __shfl(o[3][j], (lane & 48) | 15, 64);
        float inv = 1.f / l;
        int t = qbase + wq * 16 + lg * 4 + j;
        #pragma unroll
        for (int ni = 0; ni < 4; ++ni) {
            int d = ni * 16 + lq;
            if (d < HD_)
                Y[((size_t)b * T_ + t) * KP_ + h * HD_ + d] =
                    __float2bfloat16(o[ni][j] * inv);
        }
    }
}

// ---------------------------------------------------------------------------
extern "C" void kernel_launch(void* const* d_in, const int* in_sizes, int n_in,
                              void* d_out, int out_size, void* d_ws, size_t ws_size,
                              hipStream_t stream)
{
    const float* x      = (const float*)d_in[0];
    const float* W_attn = (const float*)d_in[1];
    const float* b_attn = (const float*)d_in[2];
    const float* W_proj = (const float*)d_in[3];
    const float* b_proj = (const float*)d_in[4];
    float* out = (float*)d_out;

    __hip_bfloat16* xb = (__hip_bfloat16*)d_ws;                        // [8192][1088]
    unsigned short* qb = (unsigned short*)(xb + (size_t)M_ * KP_);     // [bh][t][64]
    unsigned short* kb = qb + (size_t)NBT_ * DP_;
    unsigned short* vtb = kb + (size_t)NBT_ * DP_;                     // [bh][64][t]
    __hip_bfloat16* wta = (__hip_bfloat16*)(vtb + (size_t)NBT_ * DP_); // [3840][1088]
    __hip_bfloat16* wtp = wta + (size_t)NQKV_ * KP_;                   // [1152][1088]
    float* bp = (float*)(wtp + (size_t)NPRJ_ * KP_);                   // [3840]
    __hip_bfloat16* yb = xb;   // alias: xb fully consumed before attn writes y

    // 0) ALL preprocessing in one launch
    prep_all<<<PB_CVT + PB_WTA + PB_WTP + 15, 256, 0, stream>>>(
        x, W_attn, W_proj, b_attn, xb, wta, wtp, bp);

    // 1) QKV projection: 256-tile BK=32 GEMM (2 blocks/CU, one dispatch round)
    gemm256<<<dim3(NQKV_ / 256, M_ / 256), 512, 0, stream>>>(
        (const unsigned short*)xb, (const unsigned short*)wta, bp,
        qb, kb, vtb);

    // 2) MFMA flash attention, 2 q-tiles/block -> yb (= xb)
    attn_mfma<<<dim3(T_ / 128, B_ * H_), 512, 0, stream>>>(qb, kb, vtb, yb);

    // 3) output projection -> d_out fp32
    gemm_mfma_p<<<dim3(NPRJ_ / 128, M_ / 128), 256, 0, stream>>>(
        (const unsigned short*)yb, (const unsigned short*)wtp, b_proj, out);
}

// Round 17
// 162.956 us; speedup vs baseline: 1.0598x; 1.0598x over previous
//
#include <hip/hip_runtime.h>
#include <hip/hip_bf16.h>

#define B_   16
#define T_   512
#define C_   1080
#define H_   20
#define HD_  54
#define DP_  64                 // padded head dim
#define M_   (B_ * T_)          // 8192
#define KP_  1088               // padded K (17*64)
#define NT_  17                 // K tiles of 64
#define NQKV_ 3840              // padded 3C: 3 * 20 * 64
#define NPRJ_ 1152              // padded C (9*128)
#define NBT_ (B_ * H_ * T_)     // 163840

typedef short bf16x8 __attribute__((ext_vector_type(8)));
typedef float f32x4  __attribute__((ext_vector_type(4)));
typedef unsigned short u16x8 __attribute__((ext_vector_type(8)));

__device__ __forceinline__ void gload_lds16(const void* g, void* l) {
    __builtin_amdgcn_global_load_lds(
        (const __attribute__((address_space(1))) void*)g,
        (__attribute__((address_space(3))) void*)l,
        16, 0, 0);
}

__device__ __forceinline__ unsigned short f2b(float x) {
    return __builtin_bit_cast(unsigned short, __float2bfloat16(x));
}

// ---------------------------------------------------------------------------
// prep_all: (a) x -> xb bf16 cvt+pad, (b) W_attn -> wta head-padded transpose,
// (c) W_proj -> wtp transpose, (d) padded bias with V ones-column d=63.
// ---------------------------------------------------------------------------
#define PB_CVT  8704            // M_*(KP_/4)/256
#define PB_WTA  4080            // 120*34
#define PB_WTP  1224            // 36*34
__global__ __launch_bounds__(256) void prep_all(
    const float* __restrict__ x, const float* __restrict__ W_attn,
    const float* __restrict__ W_proj, const float* __restrict__ b_attn,
    __hip_bfloat16* __restrict__ xb,
    __hip_bfloat16* __restrict__ wta, __hip_bfloat16* __restrict__ wtp,
    float* __restrict__ bp)
{
    __shared__ float tile[32][33];
    int id = blockIdx.x;

    if (id < PB_CVT) {
        int idx = id * 256 + threadIdx.x;
        int m = idx / (KP_ / 4), c = idx - m * (KP_ / 4);
        ushort4 o;
        if (c < C_ / 4) {
            float4 v = *reinterpret_cast<const float4*>(x + (size_t)m * C_ + c * 4);
            o.x = f2b(v.x); o.y = f2b(v.y); o.z = f2b(v.z); o.w = f2b(v.w);
        } else {
            o.x = o.y = o.z = o.w = 0;
        }
        *reinterpret_cast<ushort4*>(reinterpret_cast<unsigned short*>(xb) +
                                    (size_t)m * KP_ + c * 4) = o;
        return;
    }
    id -= PB_CVT;
    const int tx = threadIdx.x & 31, ty = threadIdx.x >> 5;

    if (id < PB_WTA) {
        int bx = id % 120, by = id / 120;
        int n0 = bx * 32, k0 = by * 32;
        int np = n0 + tx;
        int which = np / 1280;
        int rem = np - which * 1280;
        int h = rem >> 6, d = rem & 63;
        int sn = which * C_ + h * HD_ + d;
        bool valid = d < HD_;
        #pragma unroll
        for (int i = 0; i < 32; i += 8) {
            int k = k0 + ty + i;
            tile[ty + i][tx] = (valid && k < C_) ? W_attn[(size_t)k * (3 * C_) + sn] : 0.f;
        }
        __syncthreads();
        #pragma unroll
        for (int i = 0; i < 32; i += 8) {
            int n = n0 + ty + i, k = k0 + tx;
            wta[(size_t)n * KP_ + k] = __float2bfloat16(tile[tx][ty + i]);
        }
        return;
    }
    id -= PB_WTA;

    if (id < PB_WTP) {
        int bx = id % 36, by = id / 36;
        int n0 = bx * 32, k0 = by * 32;
        #pragma unroll
        for (int i = 0; i < 32; i += 8) {
            int k = k0 + ty + i, n = n0 + tx;
            tile[ty + i][tx] = (k < C_ && n < C_) ? W_proj[(size_t)k * C_ + n] : 0.f;
        }
        __syncthreads();
        #pragma unroll
        for (int i = 0; i < 32; i += 8) {
            int n = n0 + ty + i, k = k0 + tx;
            wtp[(size_t)n * KP_ + k] = __float2bfloat16(tile[tx][ty + i]);
        }
        return;
    }
    id -= PB_WTP;

    {
        int i = id * 256 + threadIdx.x;
        if (i < NQKV_) {
            int which = i / 1280, rem = i - which * 1280;
            int h = rem >> 6, d = rem & 63;
            float v = (d < HD_) ? b_attn[which * C_ + h * HD_ + d] : 0.f;
            if (which == 2 && d == 63) v = 1.0f;
            bp[i] = v;
        }
    }
}

// ---------------------------------------------------------------------------
// 256x256 8-wave MFMA GEMM for QKV -- m201 8-phase template (r15 best: 73us,
// MfmaUtil 38%). Iteration = 2 K-tiles, 8 phases, each {ds-reads | 1 half-tile
// stage | barrier | lgkm(0)+schedbar | 16 MFMA | barrier}; vmcnt(4) only at
// ph3/ph7. BK=32 variant REGRESSED (r16: 4-way bank conflicts, 6.5M); keep BK=64.
// ---------------------------------------------------------------------------
#define BAR_() __builtin_amdgcn_s_barrier()
#define LGKM0_() do { asm volatile("s_waitcnt lgkmcnt(0)" ::: "memory"); \
                      __builtin_amdgcn_sched_barrier(0); } while (0)
#define MFMA_QUAD(Q) do { __builtin_amdgcn_s_setprio(1);                      \
    _Pragma("unroll") for (int kk = 0; kk < 2; ++kk)                          \
    _Pragma("unroll") for (int i = 0; i < 2; ++i)                             \
    _Pragma("unroll") for (int ni = 0; ni < 4; ++ni)                          \
        acc[(Q) * 2 + i][ni] = __builtin_amdgcn_mfma_f32_16x16x32_bf16(       \
            af[kk][i], bfr[ni][kk], acc[(Q) * 2 + i][ni], 0, 0, 0);           \
    __builtin_amdgcn_s_setprio(0); } while (0)

__global__ __launch_bounds__(512, 2) void gemm256(
    const unsigned short* __restrict__ A,
    const unsigned short* __restrict__ Bt,
    const float* __restrict__ bias,
    unsigned short* __restrict__ outQ,
    unsigned short* __restrict__ outK,
    unsigned short* __restrict__ outV)
{
    __shared__ __align__(16) char smem[131072];

    const int tid  = threadIdx.x;
    const int lane = tid & 63;
    const int wv   = tid >> 6;
    const int wr   = wv >> 2;          // m-half 0..1
    const int wc   = wv & 3;           // n-quarter 0..3
    const int lq   = lane & 15;
    const int lg   = lane >> 4;

    // XCD swizzle: 480 blocks, chunk = 4 m-tiles, m-fastest walk
    const int id  = blockIdx.y * 15 + blockIdx.x;
    const int xcd = id & 7;
    const int j   = id >> 3;
    const int m0  = (xcd * 4 + (j & 3)) * 256;
    const int n0  = (j >> 2) * 256;

    // staging offsets: per half-tile (16KB) each thread loads 2 x 16B chunks
    unsigned gA[2], gB[2];
    const int ld0 = tid * 16, ld1 = tid * 16 + 8192;
    #pragma unroll
    for (int i = 0; i < 2; ++i) {
        int ci = tid + i * 512;
        int r  = ci >> 3;
        int kc = (ci & 7) ^ (r & 7);
        gA[i] = (unsigned)(m0 + r) * KP_ + kc * 8;
        gB[i] = (unsigned)(n0 + r) * KP_ + kc * 8;
    }
    const unsigned HALFSTEP = 128u * KP_;

    // stage 1 half-tile (2 gload_lds): hIdx 0,1 = A halves; 2,3 = B halves
    auto stage = [&](int buf, int hIdx, unsigned k0) {
        char* sb = smem + buf * 65536 +
                   (hIdx < 2 ? hIdx * 16384 : 32768 + (hIdx - 2) * 16384);
        const unsigned short* sp = (hIdx < 2) ? A : Bt;
        unsigned extra = (hIdx & 1) ? HALFSTEP : 0u;
        gload_lds16(sp + ((hIdx < 2) ? gA[0] : gB[0]) + extra + k0, sb + ld0);
        gload_lds16(sp + ((hIdx < 2) ? gA[1] : gB[1]) + extra + k0, sb + ld1);
    };

    // ds_read bases
    const int s0 = (lg ^ (lq & 7)) * 16;
    const int s1 = ((4 + lg) ^ (lq & 7)) * 16;
    const int aBase = wr * 16384 + lq * 128;
    const int bBase = 32768 + (wc >> 1) * 16384 + (wc & 1) * 8192 + lq * 128;

    auto readA = [&](const char* Ab, int q, bf16x8 (&af)[2][2]) {
        #pragma unroll
        for (int i = 0; i < 2; ++i) {
            af[0][i] = *reinterpret_cast<const bf16x8*>(Ab + (q * 2 + i) * 2048 + s0);
            af[1][i] = *reinterpret_cast<const bf16x8*>(Ab + (q * 2 + i) * 2048 + s1);
        }
    };
    auto readB = [&](const char* Bb, bf16x8 (&bfr)[4][2]) {
        #pragma unroll
        for (int ni = 0; ni < 4; ++ni) {
            bfr[ni][0] = *reinterpret_cast<const bf16x8*>(Bb + ni * 2048 + s0);
            bfr[ni][1] = *reinterpret_cast<const bf16x8*>(Bb + ni * 2048 + s1);
        }
    };

    f32x4 acc[8][4] = {};

    // prologue: B(0), A(0), B(1); keep B(1) in flight
    stage(0, 2, 0); stage(0, 3, 0);
    stage(0, 0, 0); stage(0, 1, 0);
    stage(1, 2, 64); stage(1, 3, 64);
    asm volatile("s_waitcnt vmcnt(4)" ::: "memory");
    BAR_();

    const char* Ab0 = smem + aBase;
    const char* Bb0 = smem + bBase;
    const char* Ab1 = smem + 65536 + aBase;
    const char* Bb1 = smem + 65536 + bBase;

    for (int it = 0; it < 8; ++it) {
        const unsigned kT1 = (unsigned)(2 * it + 1) * 64;
        const unsigned kT2 = (unsigned)(2 * it + 2) * 64;
        const unsigned kT3 = (unsigned)(2 * it + 3) * 64;
        const bool lastIt = (it == 7);
        bf16x8 bfr[4][2], af[2][2];

        // ph0: T0 quad0 | stage A0,A1(T1) -> buf1
        readB(Bb0, bfr); readA(Ab0, 0, af);
        stage(1, 0, kT1); stage(1, 1, kT1);
        BAR_(); LGKM0_(); MFMA_QUAD(0); BAR_();
        // ph1: T0 quad1 | stage B0(T2) -> buf0
        readA(Ab0, 1, af);
        stage(0, 2, kT2);
        BAR_(); LGKM0_(); MFMA_QUAD(1); BAR_();
        // ph2: T0 quad2 | stage B1(T2)
        readA(Ab0, 2, af);
        stage(0, 3, kT2);
        BAR_(); LGKM0_(); MFMA_QUAD(2); BAR_();
        // ph3: T0 quad3 | vmcnt(4): forces B(T1),A(T1) landed (keeps B(T2))
        readA(Ab0, 3, af);
        asm volatile("s_waitcnt vmcnt(4)" ::: "memory");
        BAR_(); LGKM0_(); MFMA_QUAD(3); BAR_();
        // ph4: T1 quad0 | stage A0,A1(T2) -> buf0
        readB(Bb1, bfr); readA(Ab1, 0, af);
        stage(0, 0, kT2); stage(0, 1, kT2);
        BAR_(); LGKM0_(); MFMA_QUAD(0); BAR_();
        // ph5: T1 quad1 | stage B0(T3) (skip on last iter)
        readA(Ab1, 1, af);
        if (!lastIt) stage(1, 2, kT3);
        BAR_(); LGKM0_(); MFMA_QUAD(1); BAR_();
        // ph6: T1 quad2 | stage B1(T3) (skip on last iter)
        readA(Ab1, 2, af);
        if (!lastIt) stage(1, 3, kT3);
        BAR_(); LGKM0_(); MFMA_QUAD(2); BAR_();
        // ph7: T1 quad3 | vmcnt(4) (last iter: full drain for the tail)
        readA(Ab1, 3, af);
        if (!lastIt) asm volatile("s_waitcnt vmcnt(4)" ::: "memory");
        else         asm volatile("s_waitcnt vmcnt(0)" ::: "memory");
        BAR_(); LGKM0_(); MFMA_QUAD(3); BAR_();
    }

    // tail: K-tile 16 in buf0 (landed+barriered; no staging -> barrier-free)
    {
        bf16x8 bfr[4][2], af[2][2];
        readB(Bb0, bfr);
        readA(Ab0, 0, af); LGKM0_(); MFMA_QUAD(0);
        readA(Ab0, 1, af); LGKM0_(); MFMA_QUAD(1);
        readA(Ab0, 2, af); LGKM0_(); MFMA_QUAD(2);
        readA(Ab0, 3, af); LGKM0_(); MFMA_QUAD(3);
    }
    __syncthreads();

    // epilogue
    const int which = n0 / 1280;       // block-uniform (1280 % 256 == 0)
    if (which < 2) {
        unsigned short* dst = which ? outK : outQ;
        #pragma unroll
        for (int mi = 0; mi < 8; ++mi) {
            int mg = m0 + wr * 128 + mi * 16 + lg * 4;
            int b = mg >> 9, t0 = mg & (T_ - 1);
            #pragma unroll
            for (int ni = 0; ni < 4; ++ni) {
                int nl = wc * 64 + ni * 16 + lq;
                int ng = n0 + nl - which * 1280;
                int h = ng >> 6, d = ng & 63;
                float bs = bias[n0 + nl];
                size_t basei = ((size_t)(b * H_ + h) * T_ + t0) * DP_ + d;
                #pragma unroll
                for (int j2 = 0; j2 < 4; ++j2)
                    dst[basei + (size_t)j2 * DP_] = f2b(acc[mi][ni][j2] + bs);
            }
        }
    } else {
        // V: 2-pass (m-half) skewed LDS transpose + 16B coalesced stores
        unsigned short* lt = (unsigned short*)smem;   // [256 n][136 m-half]
        #pragma unroll
        for (int hm = 0; hm < 2; ++hm) {
            if (hm == 1) __syncthreads();
            if (wr == hm) {
                #pragma unroll
                for (int mi = 0; mi < 8; ++mi) {
                    int ml = mi * 16 + lg * 4;
                    int mc = ml >> 3, mo = ml & 7;
                    #pragma unroll
                    for (int ni = 0; ni < 4; ++ni) {
                        int nl = wc * 64 + ni * 16 + lq;
                        float bs = bias[n0 + nl];
                        ushort4 pk;
                        pk.x = f2b(acc[mi][ni][0] + bs);
                        pk.y = f2b(acc[mi][ni][1] + bs);
                        pk.z = f2b(acc[mi][ni][2] + bs);
                        pk.w = f2b(acc[mi][ni][3] + bs);
                        int slot = mc ^ ((nl >> 3) & 15);
                        *reinterpret_cast<ushort4*>(lt + nl * 136 + slot * 8 + mo) = pk;
                    }
                }
            }
            __syncthreads();
            #pragma unroll
            for (int it = 0; it < 8; ++it) {
                int idx = it * 512 + tid;
                int c2 = idx >> 4, j2 = idx & 15;
                int slot = j2 ^ ((c2 >> 3) & 15);
                u16x8 v = *reinterpret_cast<const u16x8*>(lt + c2 * 136 + slot * 8);
                int ng = n0 + c2 - 2560;
                int h = ng >> 6, d = ng & 63;
                int mg = m0 + hm * 128 + j2 * 8;
                int b = mg >> 9, t = mg & (T_ - 1);
                *reinterpret_cast<u16x8*>(outV + ((size_t)(b * H_ + h) * DP_ + d) * T_ + t) = v;
            }
        }
    }
}

// ---------------------------------------------------------------------------
// 128x128 bf16 MFMA GEMM (proj): ring-2 LDS, counted vmcnt(8), hoisted addrs.
// ---------------------------------------------------------------------------
__global__ __launch_bounds__(256) void gemm_mfma_p(
    const unsigned short* __restrict__ A,
    const unsigned short* __restrict__ Bt,
    const float* __restrict__ bias,
    float* __restrict__ outP)
{
    __shared__ __align__(16) char smem[65536];

    const int tid  = threadIdx.x;
    const int lane = tid & 63;
    const int wv   = tid >> 6;
    const int wm   = (wv >> 1) * 64;
    const int wn   = (wv & 1) * 64;
    const int lr   = lane & 15;
    const int lk   = lane >> 4;

    const int gx  = gridDim.x;
    const int gy  = gridDim.y;
    const int id  = blockIdx.y * gx + blockIdx.x;
    const int xcd = id & 7;
    const int j   = id >> 3;
    const int mpc = gy >> 3;
    const int m0  = (xcd * mpc + j % mpc) * 128;
    const int n0  = (j / mpc) * 128;

    unsigned aOff[4], bOff[4];
    int ciB[4];
    #pragma unroll
    for (int it = 0; it < 4; ++it) {
        int ci = it * 256 + tid;
        int r = ci >> 3, p = ci & 7;
        int kc = p ^ (r & 7);
        aOff[it] = (unsigned)(m0 + r) * KP_ + kc * 8;
        bOff[it] = (unsigned)(n0 + r) * KP_ + kc * 8;
        ciB[it] = ci * 16;
    }
    int aRd[2][4], bRd[2][4];
    #pragma unroll
    for (int kk = 0; kk < 2; ++kk) {
        #pragma unroll
        for (int mi = 0; mi < 4; ++mi) {
            int row = wm + mi * 16 + lr;
            aRd[kk][mi] = row * 128 + ((kk * 4 + lk) ^ (row & 7)) * 16;
            int rowb = wn + mi * 16 + lr;
            bRd[kk][mi] = 16384 + rowb * 128 + ((kk * 4 + lk) ^ (rowb & 7)) * 16;
        }
    }

    f32x4 acc[4][4] = {};

    auto stage = [&](int buf, int kt) {
        const unsigned k0 = kt * 64;
        char* sb = smem + buf * 32768;
        #pragma unroll
        for (int it = 0; it < 4; ++it)
            gload_lds16(A + aOff[it] + k0, sb + ciB[it]);
        #pragma unroll
        for (int it = 0; it < 4; ++it)
            gload_lds16(Bt + bOff[it] + k0, sb + 16384 + ciB[it]);
    };

    stage(0, 0);
    for (int kt = 0; kt < NT_; ++kt) {
        const int c = kt & 1;
        if (kt + 1 < NT_) {
            stage(1 - c, kt + 1);
            asm volatile("s_waitcnt vmcnt(8)" ::: "memory");
        } else {
            asm volatile("s_waitcnt vmcnt(0)" ::: "memory");
        }
        __builtin_amdgcn_s_barrier();
        asm volatile("" ::: "memory");

        const char* base = smem + c * 32768;
        #pragma unroll
        for (int kk = 0; kk < 2; ++kk) {
            bf16x8 af[4], bfr[4];
            #pragma unroll
            for (int mi = 0; mi < 4; ++mi)
                af[mi] = *reinterpret_cast<const bf16x8*>(base + aRd[kk][mi]);
            #pragma unroll
            for (int ni = 0; ni < 4; ++ni)
                bfr[ni] = *reinterpret_cast<const bf16x8*>(base + bRd[kk][ni]);
            #pragma unroll
            for (int mi = 0; mi < 4; ++mi)
                #pragma unroll
                for (int ni = 0; ni < 4; ++ni)
                    acc[mi][ni] = __builtin_amdgcn_mfma_f32_16x16x32_bf16(
                        af[mi], bfr[ni], acc[mi][ni], 0, 0, 0);
        }
        asm volatile("" ::: "memory");
        __builtin_amdgcn_s_barrier();
    }

    #pragma unroll
    for (int mi = 0; mi < 4; ++mi) {
        int mrow = m0 + wm + mi * 16 + lk * 4;
        #pragma unroll
        for (int ni = 0; ni < 4; ++ni) {
            int n = n0 + wn + ni * 16 + lr;
            if (n < C_) {
                float bs = bias[n];
                #pragma unroll
                for (int j2 = 0; j2 < 4; ++j2)
                    outP[(size_t)(mrow + j2) * C_ + n] = acc[mi][ni][j2] + bs;
            }
        }
    }
}

// ---------------------------------------------------------------------------
// MFMA flash attention, static-max softmax + ones-column l, 2 q-tiles/block.
// ---------------------------------------------------------------------------
__global__ __launch_bounds__(512) void attn_mfma(
    const unsigned short* __restrict__ Q, const unsigned short* __restrict__ K,
    const unsigned short* __restrict__ Vt, __hip_bfloat16* __restrict__ Y)
{
    __shared__ __align__(16) char kvs[16384];               // K tile | Vt tile
    __shared__ __align__(16) unsigned short ps[8][16][72];  // per-wave P

    const int tid  = threadIdx.x;
    const int lane = tid & 63;
    const int wv   = tid >> 6;          // 0..7
    const int grp  = wv >> 2;           // q-tile within pair
    const int wq   = wv & 3;            // wave within q-tile group
    const int lq   = lane & 15;
    const int lg   = lane >> 4;
    const int bh   = blockIdx.y;
    const int qt_own = blockIdx.x * 2 + grp;
    const int qbase  = qt_own * 64;
    const float cs = 0.13608276348795434f * 1.44269504f;  // (1/sqrt(54))*log2e

    bf16x8 qf[2];
    {
        const unsigned short* qp = Q + ((size_t)bh * T_ + qbase + wq * 16 + lq) * DP_;
        qf[0] = *reinterpret_cast<const bf16x8*>(qp + lg * 8);
        qf[1] = *reinterpret_cast<const bf16x8*>(qp + 32 + lg * 8);
    }

    const int sr = tid >> 3, sp = tid & 7;
    const int spc = sp ^ (sr & 7);
    const unsigned kOff = (unsigned)(sr * DP_ + spc * 8);
    const unsigned vOff = (unsigned)(sr * T_ + spc * 8);
    const unsigned short* Kb = K  + (size_t)bh * T_ * DP_;
    const unsigned short* Vb = Vt + (size_t)bh * DP_ * T_;

    f32x4 o[4] = {};
    unsigned short* pbase = &ps[wv][0][0];
    const int nt = blockIdx.x * 2 + 2;

    for (int kt = 0; kt < nt; ++kt) {
        const int kbase = kt * 64;
        gload_lds16(Kb + kOff + (unsigned)kbase * DP_, kvs + tid * 16);
        gload_lds16(Vb + vOff + (unsigned)kbase, kvs + 8192 + tid * 16);
        __syncthreads();

        if (kt <= qt_own) {               // wave-uniform causal tile guard
            f32x4 s[4] = {};
            __builtin_amdgcn_s_setprio(1);
            #pragma unroll
            for (int dc = 0; dc < 2; ++dc) {
                #pragma unroll
                for (int ni = 0; ni < 4; ++ni) {
                    int row = ni * 16 + lq;
                    int ch  = (dc * 4 + lg) ^ (row & 7);
                    bf16x8 kf = *reinterpret_cast<const bf16x8*>(kvs + row * 128 + ch * 16);
                    s[ni] = __builtin_amdgcn_mfma_f32_16x16x32_bf16(qf[dc], kf, s[ni], 0, 0, 0);
                }
            }
            __builtin_amdgcn_s_setprio(0);

            if (kt == qt_own) {
                #pragma unroll
                for (int ni = 0; ni < 4; ++ni) {
                    int kg = kbase + ni * 16 + lq;
                    #pragma unroll
                    for (int j = 0; j < 4; ++j) {
                        int qg = qbase + wq * 16 + lg * 4 + j;
                        s[ni][j] = (kg > qg) ? -3.0e38f : s[ni][j];
                    }
                }
            }
            #pragma unroll
            for (int ni = 0; ni < 4; ++ni) {
                #pragma unroll
                for (int j = 0; j < 4; ++j) {
                    float p = exp2f(s[ni][j] * cs);
                    int qr = lg * 4 + j;
                    int cidx = (ni * 2 + (lq >> 3)) ^ (qr & 7);
                    pbase[qr * 72 + cidx * 8 + (lq & 7)] = f2b(p);
                }
            }

            asm volatile("s_waitcnt lgkmcnt(0)" ::: "memory");
            __builtin_amdgcn_sched_barrier(0);

            __builtin_amdgcn_s_setprio(1);
            #pragma unroll
            for (int dc = 0; dc < 2; ++dc) {
                int cc = (dc * 4 + lg) ^ (lq & 7);
                bf16x8 pf = *reinterpret_cast<const bf16x8*>(pbase + lq * 72 + cc * 8);
                #pragma unroll
                for (int ni = 0; ni < 4; ++ni) {
                    int row = ni * 16 + lq;
                    int ch  = (dc * 4 + lg) ^ (row & 7);
                    bf16x8 vf = *reinterpret_cast<const bf16x8*>(kvs + 8192 + row * 128 + ch * 16);
                    o[ni] = __builtin_amdgcn_mfma_f32_16x16x32_bf16(pf, vf, o[ni], 0, 0, 0);
                }
            }
            __builtin_amdgcn_s_setprio(0);
        }
        __syncthreads();
    }

    const int b = bh / H_, h = bh - b * H_;
    #pragma unroll
    for (int j = 0; j < 4; ++j) {
        float l = __shfl(o[3][j], (lane & 48) | 15, 64);
        float inv = 1.f / l;
        int t = qbase + wq * 16 + lg * 4 + j;
        #pragma unroll
        for (int ni = 0; ni < 4; ++ni) {
            int d = ni * 16 + lq;
            if (d < HD_)
                Y[((size_t)b * T_ + t) * KP_ + h * HD_ + d] =
                    __float2bfloat16(o[ni][j] * inv);
        }
    }
}

// ---------------------------------------------------------------------------
extern "C" void kernel_launch(void* const* d_in, const int* in_sizes, int n_in,
                              void* d_out, int out_size, void* d_ws, size_t ws_size,
                              hipStream_t stream)
{
    const float* x      = (const float*)d_in[0];
    const float* W_attn = (const float*)d_in[1];
    const float* b_attn = (const float*)d_in[2];
    const float* W_proj = (const float*)d_in[3];
    const float* b_proj = (const float*)d_in[4];
    float* out = (float*)d_out;

    __hip_bfloat16* xb = (__hip_bfloat16*)d_ws;                        // [8192][1088]
    unsigned short* qb = (unsigned short*)(xb + (size_t)M_ * KP_);     // [bh][t][64]
    unsigned short* kb = qb + (size_t)NBT_ * DP_;
    unsigned short* vtb = kb + (size_t)NBT_ * DP_;                     // [bh][64][t]
    __hip_bfloat16* wta = (__hip_bfloat16*)(vtb + (size_t)NBT_ * DP_); // [3840][1088]
    __hip_bfloat16* wtp = wta + (size_t)NQKV_ * KP_;                   // [1152][1088]
    float* bp = (float*)(wtp + (size_t)NPRJ_ * KP_);                   // [3840]
    __hip_bfloat16* yb = xb;   // alias: xb fully consumed before attn writes y

    // 0) ALL preprocessing in one launch
    prep_all<<<PB_CVT + PB_WTA + PB_WTP + 15, 256, 0, stream>>>(
        x, W_attn, W_proj, b_attn, xb, wta, wtp, bp);

    // 1) QKV projection: 256-tile 8-wave GEMM, m201 8-phase schedule
    gemm256<<<dim3(NQKV_ / 256, M_ / 256), 512, 0, stream>>>(
        (const unsigned short*)xb, (const unsigned short*)wta, bp,
        qb, kb, vtb);

    // 2) MFMA flash attention, 2 q-tiles/block -> yb (= xb)
    attn_mfma<<<dim3(T_ / 128, B_ * H_), 512, 0, stream>>>(qb, kb, vtb, yb);

    // 3) output projection -> d_out fp32
    gemm_mfma_p<<<dim3(NPRJ_ / 128, M_ / 128), 256, 0, stream>>>(
        (const unsigned short*)yb, (const unsigned short*)wtp, b_proj, out);
}

// Round 18
// 159.592 us; speedup vs baseline: 1.0821x; 1.0211x over previous
//
#include <hip/hip_runtime.h>
#include <hip/hip_bf16.h>

#define B_   16
#define T_   512
#define C_   1080
#define H_   20
#define HD_  54
#define DP_  64                 // padded head dim
#define M_   (B_ * T_)          // 8192
#define KP_  1088               // padded K (17*64)
#define NT_  17                 // K tiles of 64
#define NQKV_ 3840              // padded 3C: 3 * 20 * 64
#define NPRJ_ 1152              // padded C (9*128)
#define NBT_ (B_ * H_ * T_)     // 163840

typedef short bf16x8 __attribute__((ext_vector_type(8)));
typedef float f32x4  __attribute__((ext_vector_type(4)));
typedef unsigned short u16x8 __attribute__((ext_vector_type(8)));

__device__ __forceinline__ void gload_lds16(const void* g, void* l) {
    __builtin_amdgcn_global_load_lds(
        (const __attribute__((address_space(1))) void*)g,
        (__attribute__((address_space(3))) void*)l,
        16, 0, 0);
}

__device__ __forceinline__ unsigned short f2b(float x) {
    return __builtin_bit_cast(unsigned short, __float2bfloat16(x));
}

// ---------------------------------------------------------------------------
// prep_all: (a) x -> xb bf16 cvt+pad, (b) W_attn -> wta head-padded transpose,
// (c) W_proj -> wtp transpose, (d) padded bias with V ones-column d=63.
// ---------------------------------------------------------------------------
#define PB_CVT  8704            // M_*(KP_/4)/256
#define PB_WTA  4080            // 120*34
#define PB_WTP  1224            // 36*34
__global__ __launch_bounds__(256) void prep_all(
    const float* __restrict__ x, const float* __restrict__ W_attn,
    const float* __restrict__ W_proj, const float* __restrict__ b_attn,
    __hip_bfloat16* __restrict__ xb,
    __hip_bfloat16* __restrict__ wta, __hip_bfloat16* __restrict__ wtp,
    float* __restrict__ bp)
{
    __shared__ float tile[32][33];
    int id = blockIdx.x;

    if (id < PB_CVT) {
        int idx = id * 256 + threadIdx.x;
        int m = idx / (KP_ / 4), c = idx - m * (KP_ / 4);
        ushort4 o;
        if (c < C_ / 4) {
            float4 v = *reinterpret_cast<const float4*>(x + (size_t)m * C_ + c * 4);
            o.x = f2b(v.x); o.y = f2b(v.y); o.z = f2b(v.z); o.w = f2b(v.w);
        } else {
            o.x = o.y = o.z = o.w = 0;
        }
        *reinterpret_cast<ushort4*>(reinterpret_cast<unsigned short*>(xb) +
                                    (size_t)m * KP_ + c * 4) = o;
        return;
    }
    id -= PB_CVT;
    const int tx = threadIdx.x & 31, ty = threadIdx.x >> 5;

    if (id < PB_WTA) {
        int bx = id % 120, by = id / 120;
        int n0 = bx * 32, k0 = by * 32;
        int np = n0 + tx;
        int which = np / 1280;
        int rem = np - which * 1280;
        int h = rem >> 6, d = rem & 63;
        int sn = which * C_ + h * HD_ + d;
        bool valid = d < HD_;
        #pragma unroll
        for (int i = 0; i < 32; i += 8) {
            int k = k0 + ty + i;
            tile[ty + i][tx] = (valid && k < C_) ? W_attn[(size_t)k * (3 * C_) + sn] : 0.f;
        }
        __syncthreads();
        #pragma unroll
        for (int i = 0; i < 32; i += 8) {
            int n = n0 + ty + i, k = k0 + tx;
            wta[(size_t)n * KP_ + k] = __float2bfloat16(tile[tx][ty + i]);
        }
        return;
    }
    id -= PB_WTA;

    if (id < PB_WTP) {
        int bx = id % 36, by = id / 36;
        int n0 = bx * 32, k0 = by * 32;
        #pragma unroll
        for (int i = 0; i < 32; i += 8) {
            int k = k0 + ty + i, n = n0 + tx;
            tile[ty + i][tx] = (k < C_ && n < C_) ? W_proj[(size_t)k * C_ + n] : 0.f;
        }
        __syncthreads();
        #pragma unroll
        for (int i = 0; i < 32; i += 8) {
            int n = n0 + ty + i, k = k0 + tx;
            wtp[(size_t)n * KP_ + k] = __float2bfloat16(tile[tx][ty + i]);
        }
        return;
    }
    id -= PB_WTP;

    {
        int i = id * 256 + threadIdx.x;
        if (i < NQKV_) {
            int which = i / 1280, rem = i - which * 1280;
            int h = rem >> 6, d = rem & 63;
            float v = (d < HD_) ? b_attn[which * C_ + h * HD_ + d] : 0.f;
            if (which == 2 && d == 63) v = 1.0f;
            bp[i] = v;
        }
    }
}

// ---------------------------------------------------------------------------
// Shared 8-phase machinery (twice-verified template, r15/r17).
// ---------------------------------------------------------------------------
#define BAR_() __builtin_amdgcn_s_barrier()
#define LGKM0_() do { asm volatile("s_waitcnt lgkmcnt(0)" ::: "memory"); \
                      __builtin_amdgcn_sched_barrier(0); } while (0)
#define MFMA_QUAD(Q) do { __builtin_amdgcn_s_setprio(1);                      \
    _Pragma("unroll") for (int kk = 0; kk < 2; ++kk)                          \
    _Pragma("unroll") for (int i = 0; i < 2; ++i)                             \
    _Pragma("unroll") for (int ni = 0; ni < 4; ++ni)                          \
        acc[(Q) * 2 + i][ni] = __builtin_amdgcn_mfma_f32_16x16x32_bf16(       \
            af[kk][i], bfr[ni][kk], acc[(Q) * 2 + i][ni], 0, 0, 0);           \
    __builtin_amdgcn_s_setprio(0); } while (0)
#define MFMA_QUAD_P(Q) do { __builtin_amdgcn_s_setprio(1);                    \
    _Pragma("unroll") for (int kk = 0; kk < 2; ++kk)                          \
    _Pragma("unroll") for (int ni = 0; ni < 4; ++ni)                          \
        acc[(Q)][ni] = __builtin_amdgcn_mfma_f32_16x16x32_bf16(               \
            af[kk], bfr[ni][kk], acc[(Q)][ni], 0, 0, 0);                      \
    __builtin_amdgcn_s_setprio(0); } while (0)

// ---------------------------------------------------------------------------
// 256x256 8-wave MFMA GEMM for QKV -- m201 8-phase template (r15/r17 best:
// 73us, MfmaUtil 38.8%). UNCHANGED.
// ---------------------------------------------------------------------------
__global__ __launch_bounds__(512, 2) void gemm256(
    const unsigned short* __restrict__ A,
    const unsigned short* __restrict__ Bt,
    const float* __restrict__ bias,
    unsigned short* __restrict__ outQ,
    unsigned short* __restrict__ outK,
    unsigned short* __restrict__ outV)
{
    __shared__ __align__(16) char smem[131072];

    const int tid  = threadIdx.x;
    const int lane = tid & 63;
    const int wv   = tid >> 6;
    const int wr   = wv >> 2;          // m-half 0..1
    const int wc   = wv & 3;           // n-quarter 0..3
    const int lq   = lane & 15;
    const int lg   = lane >> 4;

    // XCD swizzle: 480 blocks, chunk = 4 m-tiles, m-fastest walk
    const int id  = blockIdx.y * 15 + blockIdx.x;
    const int xcd = id & 7;
    const int j   = id >> 3;
    const int m0  = (xcd * 4 + (j & 3)) * 256;
    const int n0  = (j >> 2) * 256;

    // staging offsets: per half-tile (16KB) each thread loads 2 x 16B chunks
    unsigned gA[2], gB[2];
    const int ld0 = tid * 16, ld1 = tid * 16 + 8192;
    #pragma unroll
    for (int i = 0; i < 2; ++i) {
        int ci = tid + i * 512;
        int r  = ci >> 3;
        int kc = (ci & 7) ^ (r & 7);
        gA[i] = (unsigned)(m0 + r) * KP_ + kc * 8;
        gB[i] = (unsigned)(n0 + r) * KP_ + kc * 8;
    }
    const unsigned HALFSTEP = 128u * KP_;

    auto stage = [&](int buf, int hIdx, unsigned k0) {
        char* sb = smem + buf * 65536 +
                   (hIdx < 2 ? hIdx * 16384 : 32768 + (hIdx - 2) * 16384);
        const unsigned short* sp = (hIdx < 2) ? A : Bt;
        unsigned extra = (hIdx & 1) ? HALFSTEP : 0u;
        gload_lds16(sp + ((hIdx < 2) ? gA[0] : gB[0]) + extra + k0, sb + ld0);
        gload_lds16(sp + ((hIdx < 2) ? gA[1] : gB[1]) + extra + k0, sb + ld1);
    };

    // ds_read bases
    const int s0 = (lg ^ (lq & 7)) * 16;
    const int s1 = ((4 + lg) ^ (lq & 7)) * 16;
    const int aBase = wr * 16384 + lq * 128;
    const int bBase = 32768 + (wc >> 1) * 16384 + (wc & 1) * 8192 + lq * 128;

    auto readA = [&](const char* Ab, int q, bf16x8 (&af)[2][2]) {
        #pragma unroll
        for (int i = 0; i < 2; ++i) {
            af[0][i] = *reinterpret_cast<const bf16x8*>(Ab + (q * 2 + i) * 2048 + s0);
            af[1][i] = *reinterpret_cast<const bf16x8*>(Ab + (q * 2 + i) * 2048 + s1);
        }
    };
    auto readB = [&](const char* Bb, bf16x8 (&bfr)[4][2]) {
        #pragma unroll
        for (int ni = 0; ni < 4; ++ni) {
            bfr[ni][0] = *reinterpret_cast<const bf16x8*>(Bb + ni * 2048 + s0);
            bfr[ni][1] = *reinterpret_cast<const bf16x8*>(Bb + ni * 2048 + s1);
        }
    };

    f32x4 acc[8][4] = {};

    // prologue: B(0), A(0), B(1); keep B(1) in flight
    stage(0, 2, 0); stage(0, 3, 0);
    stage(0, 0, 0); stage(0, 1, 0);
    stage(1, 2, 64); stage(1, 3, 64);
    asm volatile("s_waitcnt vmcnt(4)" ::: "memory");
    BAR_();

    const char* Ab0 = smem + aBase;
    const char* Bb0 = smem + bBase;
    const char* Ab1 = smem + 65536 + aBase;
    const char* Bb1 = smem + 65536 + bBase;

    for (int it = 0; it < 8; ++it) {
        const unsigned kT1 = (unsigned)(2 * it + 1) * 64;
        const unsigned kT2 = (unsigned)(2 * it + 2) * 64;
        const unsigned kT3 = (unsigned)(2 * it + 3) * 64;
        const bool lastIt = (it == 7);
        bf16x8 bfr[4][2], af[2][2];

        // ph0: T0 quad0 | stage A0,A1(T1) -> buf1
        readB(Bb0, bfr); readA(Ab0, 0, af);
        stage(1, 0, kT1); stage(1, 1, kT1);
        BAR_(); LGKM0_(); MFMA_QUAD(0); BAR_();
        // ph1: T0 quad1 | stage B0(T2) -> buf0
        readA(Ab0, 1, af);
        stage(0, 2, kT2);
        BAR_(); LGKM0_(); MFMA_QUAD(1); BAR_();
        // ph2: T0 quad2 | stage B1(T2)
        readA(Ab0, 2, af);
        stage(0, 3, kT2);
        BAR_(); LGKM0_(); MFMA_QUAD(2); BAR_();
        // ph3: T0 quad3 | vmcnt(4): forces B(T1),A(T1) landed (keeps B(T2))
        readA(Ab0, 3, af);
        asm volatile("s_waitcnt vmcnt(4)" ::: "memory");
        BAR_(); LGKM0_(); MFMA_QUAD(3); BAR_();
        // ph4: T1 quad0 | stage A0,A1(T2) -> buf0
        readB(Bb1, bfr); readA(Ab1, 0, af);
        stage(0, 0, kT2); stage(0, 1, kT2);
        BAR_(); LGKM0_(); MFMA_QUAD(0); BAR_();
        // ph5: T1 quad1 | stage B0(T3) (skip on last iter)
        readA(Ab1, 1, af);
        if (!lastIt) stage(1, 2, kT3);
        BAR_(); LGKM0_(); MFMA_QUAD(1); BAR_();
        // ph6: T1 quad2 | stage B1(T3) (skip on last iter)
        readA(Ab1, 2, af);
        if (!lastIt) stage(1, 3, kT3);
        BAR_(); LGKM0_(); MFMA_QUAD(2); BAR_();
        // ph7: T1 quad3 | vmcnt(4) (last iter: full drain for the tail)
        readA(Ab1, 3, af);
        if (!lastIt) asm volatile("s_waitcnt vmcnt(4)" ::: "memory");
        else         asm volatile("s_waitcnt vmcnt(0)" ::: "memory");
        BAR_(); LGKM0_(); MFMA_QUAD(3); BAR_();
    }

    // tail: K-tile 16 in buf0 (landed+barriered; no staging -> barrier-free)
    {
        bf16x8 bfr[4][2], af[2][2];
        readB(Bb0, bfr);
        readA(Ab0, 0, af); LGKM0_(); MFMA_QUAD(0);
        readA(Ab0, 1, af); LGKM0_(); MFMA_QUAD(1);
        readA(Ab0, 2, af); LGKM0_(); MFMA_QUAD(2);
        readA(Ab0, 3, af); LGKM0_(); MFMA_QUAD(3);
    }
    __syncthreads();

    // epilogue
    const int which = n0 / 1280;       // block-uniform (1280 % 256 == 0)
    if (which < 2) {
        unsigned short* dst = which ? outK : outQ;
        #pragma unroll
        for (int mi = 0; mi < 8; ++mi) {
            int mg = m0 + wr * 128 + mi * 16 + lg * 4;
            int b = mg >> 9, t0 = mg & (T_ - 1);
            #pragma unroll
            for (int ni = 0; ni < 4; ++ni) {
                int nl = wc * 64 + ni * 16 + lq;
                int ng = n0 + nl - which * 1280;
                int h = ng >> 6, d = ng & 63;
                float bs = bias[n0 + nl];
                size_t basei = ((size_t)(b * H_ + h) * T_ + t0) * DP_ + d;
                #pragma unroll
                for (int j2 = 0; j2 < 4; ++j2)
                    dst[basei + (size_t)j2 * DP_] = f2b(acc[mi][ni][j2] + bs);
            }
        }
    } else {
        // V: 2-pass (m-half) skewed LDS transpose + 16B coalesced stores
        unsigned short* lt = (unsigned short*)smem;   // [256 n][136 m-half]
        #pragma unroll
        for (int hm = 0; hm < 2; ++hm) {
            if (hm == 1) __syncthreads();
            if (wr == hm) {
                #pragma unroll
                for (int mi = 0; mi < 8; ++mi) {
                    int ml = mi * 16 + lg * 4;
                    int mc = ml >> 3, mo = ml & 7;
                    #pragma unroll
                    for (int ni = 0; ni < 4; ++ni) {
                        int nl = wc * 64 + ni * 16 + lq;
                        float bs = bias[n0 + nl];
                        ushort4 pk;
                        pk.x = f2b(acc[mi][ni][0] + bs);
                        pk.y = f2b(acc[mi][ni][1] + bs);
                        pk.z = f2b(acc[mi][ni][2] + bs);
                        pk.w = f2b(acc[mi][ni][3] + bs);
                        int slot = mc ^ ((nl >> 3) & 15);
                        *reinterpret_cast<ushort4*>(lt + nl * 136 + slot * 8 + mo) = pk;
                    }
                }
            }
            __syncthreads();
            #pragma unroll
            for (int it = 0; it < 8; ++it) {
                int idx = it * 512 + tid;
                int c2 = idx >> 4, j2 = idx & 15;
                int slot = j2 ^ ((c2 >> 3) & 15);
                u16x8 v = *reinterpret_cast<const u16x8*>(lt + c2 * 136 + slot * 8);
                int ng = n0 + c2 - 2560;
                int h = ng >> 6, d = ng & 63;
                int mg = m0 + hm * 128 + j2 * 8;
                int b = mg >> 9, t = mg & (T_ - 1);
                *reinterpret_cast<u16x8*>(outV + ((size_t)(b * H_ + h) * DP_ + d) * T_ + t) = v;
            }
        }
    }
}

// ---------------------------------------------------------------------------
// 128x128 4-wave MFMA GEMM (proj) -- 8-phase template, geometric halving of
// gemm256 (half-tile 8KB still = 2 gloads/thread/stage -> identical vmcnt
// arithmetic; same XOR swizzle, same phase/barrier/WAR schedule).
// ---------------------------------------------------------------------------
__global__ __launch_bounds__(256, 2) void gemm_mfma_p(
    const unsigned short* __restrict__ A,
    const unsigned short* __restrict__ Bt,
    const float* __restrict__ bias,
    float* __restrict__ outP)
{
    __shared__ __align__(16) char smem[65536];

    const int tid  = threadIdx.x;
    const int lane = tid & 63;
    const int wv   = tid >> 6;          // 0..3
    const int wr   = wv >> 1;           // m-half 0..1
    const int wc   = wv & 1;            // n-half 0..1
    const int lq   = lane & 15;
    const int lg   = lane >> 4;

    // XCD swizzle: 576 blocks (9 n x 64 m tiles), chunk = 8 m-tiles
    const int id  = blockIdx.y * 9 + blockIdx.x;
    const int xcd = id & 7;
    const int j   = id >> 3;
    const int m0  = (xcd * 8 + (j & 7)) * 128;
    const int n0  = (j >> 3) * 128;

    // staging offsets: per half-tile (8KB = 64 rows) 2 x 16B chunks/thread
    unsigned gA[2], gB[2];
    const int ld0 = tid * 16, ld1 = tid * 16 + 4096;
    #pragma unroll
    for (int i = 0; i < 2; ++i) {
        int ci = tid + i * 256;
        int r  = ci >> 3;
        int kc = (ci & 7) ^ (r & 7);
        gA[i] = (unsigned)(m0 + r) * KP_ + kc * 8;
        gB[i] = (unsigned)(n0 + r) * KP_ + kc * 8;
    }
    const unsigned HALFSTEP = 64u * KP_;

    auto stage = [&](int buf, int hIdx, unsigned k0) {
        char* sb = smem + buf * 32768 +
                   (hIdx < 2 ? hIdx * 8192 : 16384 + (hIdx - 2) * 8192);
        const unsigned short* sp = (hIdx < 2) ? A : Bt;
        unsigned extra = (hIdx & 1) ? HALFSTEP : 0u;
        gload_lds16(sp + ((hIdx < 2) ? gA[0] : gB[0]) + extra + k0, sb + ld0);
        gload_lds16(sp + ((hIdx < 2) ? gA[1] : gB[1]) + extra + k0, sb + ld1);
    };

    // ds_read bases
    const int s0 = (lg ^ (lq & 7)) * 16;
    const int s1 = ((4 + lg) ^ (lq & 7)) * 16;
    const int aBase = wr * 8192 + lq * 128;
    const int bBase = 16384 + wc * 8192 + lq * 128;

    auto readA = [&](const char* Ab, int q, bf16x8 (&af)[2]) {
        af[0] = *reinterpret_cast<const bf16x8*>(Ab + q * 2048 + s0);
        af[1] = *reinterpret_cast<const bf16x8*>(Ab + q * 2048 + s1);
    };
    auto readB = [&](const char* Bb, bf16x8 (&bfr)[4][2]) {
        #pragma unroll
        for (int ni = 0; ni < 4; ++ni) {
            bfr[ni][0] = *reinterpret_cast<const bf16x8*>(Bb + ni * 2048 + s0);
            bfr[ni][1] = *reinterpret_cast<const bf16x8*>(Bb + ni * 2048 + s1);
        }
    };

    f32x4 acc[4][4] = {};

    // prologue: B(0), A(0), B(1); keep B(1) in flight
    stage(0, 2, 0); stage(0, 3, 0);
    stage(0, 0, 0); stage(0, 1, 0);
    stage(1, 2, 64); stage(1, 3, 64);
    asm volatile("s_waitcnt vmcnt(4)" ::: "memory");
    BAR_();

    const char* Ab0 = smem + aBase;
    const char* Bb0 = smem + bBase;
    const char* Ab1 = smem + 32768 + aBase;
    const char* Bb1 = smem + 32768 + bBase;

    for (int it = 0; it < 8; ++it) {
        const unsigned kT1 = (unsigned)(2 * it + 1) * 64;
        const unsigned kT2 = (unsigned)(2 * it + 2) * 64;
        const unsigned kT3 = (unsigned)(2 * it + 3) * 64;
        const bool lastIt = (it == 7);
        bf16x8 bfr[4][2], af[2];

        // ph0: T0 quad0 | stage A0,A1(T1) -> buf1
        readB(Bb0, bfr); readA(Ab0, 0, af);
        stage(1, 0, kT1); stage(1, 1, kT1);
        BAR_(); LGKM0_(); MFMA_QUAD_P(0); BAR_();
        // ph1: T0 quad1 | stage B0(T2) -> buf0
        readA(Ab0, 1, af);
        stage(0, 2, kT2);
        BAR_(); LGKM0_(); MFMA_QUAD_P(1); BAR_();
        // ph2: T0 quad2 | stage B1(T2)
        readA(Ab0, 2, af);
        stage(0, 3, kT2);
        BAR_(); LGKM0_(); MFMA_QUAD_P(2); BAR_();
        // ph3: T0 quad3 | vmcnt(4): forces B(T1),A(T1) landed (keeps B(T2))
        readA(Ab0, 3, af);
        asm volatile("s_waitcnt vmcnt(4)" ::: "memory");
        BAR_(); LGKM0_(); MFMA_QUAD_P(3); BAR_();
        // ph4: T1 quad0 | stage A0,A1(T2) -> buf0
        readB(Bb1, bfr); readA(Ab1, 0, af);
        stage(0, 0, kT2); stage(0, 1, kT2);
        BAR_(); LGKM0_(); MFMA_QUAD_P(0); BAR_();
        // ph5: T1 quad1 | stage B0(T3) (skip on last iter)
        readA(Ab1, 1, af);
        if (!lastIt) stage(1, 2, kT3);
        BAR_(); LGKM0_(); MFMA_QUAD_P(1); BAR_();
        // ph6: T1 quad2 | stage B1(T3) (skip on last iter)
        readA(Ab1, 2, af);
        if (!lastIt) stage(1, 3, kT3);
        BAR_(); LGKM0_(); MFMA_QUAD_P(2); BAR_();
        // ph7: T1 quad3 | vmcnt(4) (last iter: full drain for the tail)
        readA(Ab1, 3, af);
        if (!lastIt) asm volatile("s_waitcnt vmcnt(4)" ::: "memory");
        else         asm volatile("s_waitcnt vmcnt(0)" ::: "memory");
        BAR_(); LGKM0_(); MFMA_QUAD_P(3); BAR_();
    }

    // tail: K-tile 16 in buf0
    {
        bf16x8 bfr[4][2], af[2];
        readB(Bb0, bfr);
        readA(Ab0, 0, af); LGKM0_(); MFMA_QUAD_P(0);
        readA(Ab0, 1, af); LGKM0_(); MFMA_QUAD_P(1);
        readA(Ab0, 2, af); LGKM0_(); MFMA_QUAD_P(2);
        readA(Ab0, 3, af); LGKM0_(); MFMA_QUAD_P(3);
    }

    // epilogue: outP = acc + bias (fp32), n < 1080 guarded
    #pragma unroll
    for (int mi = 0; mi < 4; ++mi) {
        int mrow = m0 + wr * 64 + mi * 16 + lg * 4;
        #pragma unroll
        for (int ni = 0; ni < 4; ++ni) {
            int n = n0 + wc * 64 + ni * 16 + lq;
            if (n < C_) {
                float bs = bias[n];
                #pragma unroll
                for (int j2 = 0; j2 < 4; ++j2)
                    outP[(size_t)(mrow + j2) * C_ + n] = acc[mi][ni][j2] + bs;
            }
        }
    }
}

// ---------------------------------------------------------------------------
// MFMA flash attention, static-max softmax + ones-column l, 2 q-tiles/block.
// UNCHANGED (r13-verified).
// ---------------------------------------------------------------------------
__global__ __launch_bounds__(512) void attn_mfma(
    const unsigned short* __restrict__ Q, const unsigned short* __restrict__ K,
    const unsigned short* __restrict__ Vt, __hip_bfloat16* __restrict__ Y)
{
    __shared__ __align__(16) char kvs[16384];               // K tile | Vt tile
    __shared__ __align__(16) unsigned short ps[8][16][72];  // per-wave P

    const int tid  = threadIdx.x;
    const int lane = tid & 63;
    const int wv   = tid >> 6;          // 0..7
    const int grp  = wv >> 2;           // q-tile within pair
    const int wq   = wv & 3;            // wave within q-tile group
    const int lq   = lane & 15;
    const int lg   = lane >> 4;
    const int bh   = blockIdx.y;
    const int qt_own = blockIdx.x * 2 + grp;
    const int qbase  = qt_own * 64;
    const float cs = 0.13608276348795434f * 1.44269504f;  // (1/sqrt(54))*log2e

    bf16x8 qf[2];
    {
        const unsigned short* qp = Q + ((size_t)bh * T_ + qbase + wq * 16 + lq) * DP_;
        qf[0] = *reinterpret_cast<const bf16x8*>(qp + lg * 8);
        qf[1] = *reinterpret_cast<const bf16x8*>(qp + 32 + lg * 8);
    }

    const int sr = tid >> 3, sp = tid & 7;
    const int spc = sp ^ (sr & 7);
    const unsigned kOff = (unsigned)(sr * DP_ + spc * 8);
    const unsigned vOff = (unsigned)(sr * T_ + spc * 8);
    const unsigned short* Kb = K  + (size_t)bh * T_ * DP_;
    const unsigned short* Vb = Vt + (size_t)bh * DP_ * T_;

    f32x4 o[4] = {};
    unsigned short* pbase = &ps[wv][0][0];
    const int nt = blockIdx.x * 2 + 2;

    for (int kt = 0; kt < nt; ++kt) {
        const int kbase = kt * 64;
        gload_lds16(Kb + kOff + (unsigned)kbase * DP_, kvs + tid * 16);
        gload_lds16(Vb + vOff + (unsigned)kbase, kvs + 8192 + tid * 16);
        __syncthreads();

        if (kt <= qt_own) {               // wave-uniform causal tile guard
            f32x4 s[4] = {};
            __builtin_amdgcn_s_setprio(1);
            #pragma unroll
            for (int dc = 0; dc < 2; ++dc) {
                #pragma unroll
                for (int ni = 0; ni < 4; ++ni) {
                    int row = ni * 16 + lq;
                    int ch  = (dc * 4 + lg) ^ (row & 7);
                    bf16x8 kf = *reinterpret_cast<const bf16x8*>(kvs + row * 128 + ch * 16);
                    s[ni] = __builtin_amdgcn_mfma_f32_16x16x32_bf16(qf[dc], kf, s[ni], 0, 0, 0);
                }
            }
            __builtin_amdgcn_s_setprio(0);

            if (kt == qt_own) {
                #pragma unroll
                for (int ni = 0; ni < 4; ++ni) {
                    int kg = kbase + ni * 16 + lq;
                    #pragma unroll
                    for (int j = 0; j < 4; ++j) {
                        int qg = qbase + wq * 16 + lg * 4 + j;
                        s[ni][j] = (kg > qg) ? -3.0e38f : s[ni][j];
                    }
                }
            }
            #pragma unroll
            for (int ni = 0; ni < 4; ++ni) {
                #pragma unroll
                for (int j = 0; j < 4; ++j) {
                    float p = exp2f(s[ni][j] * cs);
                    int qr = lg * 4 + j;
                    int cidx = (ni * 2 + (lq >> 3)) ^ (qr & 7);
                    pbase[qr * 72 + cidx * 8 + (lq & 7)] = f2b(p);
                }
            }

            asm volatile("s_waitcnt lgkmcnt(0)" ::: "memory");
            __builtin_amdgcn_sched_barrier(0);

            __builtin_amdgcn_s_setprio(1);
            #pragma unroll
            for (int dc = 0; dc < 2; ++dc) {
                int cc = (dc * 4 + lg) ^ (lq & 7);
                bf16x8 pf = *reinterpret_cast<const bf16x8*>(pbase + lq * 72 + cc * 8);
                #pragma unroll
                for (int ni = 0; ni < 4; ++ni) {
                    int row = ni * 16 + lq;
                    int ch  = (dc * 4 + lg) ^ (row & 7);
                    bf16x8 vf = *reinterpret_cast<const bf16x8*>(kvs + 8192 + row * 128 + ch * 16);
                    o[ni] = __builtin_amdgcn_mfma_f32_16x16x32_bf16(pf, vf, o[ni], 0, 0, 0);
                }
            }
            __builtin_amdgcn_s_setprio(0);
        }
        __syncthreads();
    }

    const int b = bh / H_, h = bh - b * H_;
    #pragma unroll
    for (int j = 0; j < 4; ++j) {
        float l = __shfl(o[3][j], (lane & 48) | 15, 64);
        float inv = 1.f / l;
        int t = qbase + wq * 16 + lg * 4 + j;
        #pragma unroll
        for (int ni = 0; ni < 4; ++ni) {
            int d = ni * 16 + lq;
            if (d < HD_)
                Y[((size_t)b * T_ + t) * KP_ + h * HD_ + d] =
                    __float2bfloat16(o[ni][j] * inv);
        }
    }
}

// ---------------------------------------------------------------------------
extern "C" void kernel_launch(void* const* d_in, const int* in_sizes, int n_in,
                              void* d_out, int out_size, void* d_ws, size_t ws_size,
                              hipStream_t stream)
{
    const float* x      = (const float*)d_in[0];
    const float* W_attn = (const float*)d_in[1];
    const float* b_attn = (const float*)d_in[2];
    const float* W_proj = (const float*)d_in[3];
    const float* b_proj = (const float*)d_in[4];
    float* out = (float*)d_out;

    __hip_bfloat16* xb = (__hip_bfloat16*)d_ws;                        // [8192][1088]
    unsigned short* qb = (unsigned short*)(xb + (size_t)M_ * KP_);     // [bh][t][64]
    unsigned short* kb = qb + (size_t)NBT_ * DP_;
    unsigned short* vtb = kb + (size_t)NBT_ * DP_;                     // [bh][64][t]
    __hip_bfloat16* wta = (__hip_bfloat16*)(vtb + (size_t)NBT_ * DP_); // [3840][1088]
    __hip_bfloat16* wtp = wta + (size_t)NQKV_ * KP_;                   // [1152][1088]
    float* bp = (float*)(wtp + (size_t)NPRJ_ * KP_);                   // [3840]
    __hip_bfloat16* yb = xb;   // alias: xb fully consumed before attn writes y

    // 0) ALL preprocessing in one launch
    prep_all<<<PB_CVT + PB_WTA + PB_WTP + 15, 256, 0, stream>>>(
        x, W_attn, W_proj, b_attn, xb, wta, wtp, bp);

    // 1) QKV projection: 256-tile 8-wave GEMM, m201 8-phase schedule
    gemm256<<<dim3(NQKV_ / 256, M_ / 256), 512, 0, stream>>>(
        (const unsigned short*)xb, (const unsigned short*)wta, bp,
        qb, kb, vtb);

    // 2) MFMA flash attention, 2 q-tiles/block -> yb (= xb)
    attn_mfma<<<dim3(T_ / 128, B_ * H_), 512, 0, stream>>>(qb, kb, vtb, yb);

    // 3) output projection: 128-tile 4-wave 8-phase GEMM -> d_out fp32
    gemm_mfma_p<<<dim3(NPRJ_ / 128, M_ / 128), 256, 0, stream>>>(
        (const unsigned short*)yb, (const unsigned short*)wtp, b_proj, out);
}